// Round 4
// baseline (316.126 us; speedup 1.0000x reference)
//
#include <hip/hip_runtime.h>
#include <stdint.h>

constexpr int S = 1024;
constexpr int D = 1024;
constexpr int NB = 8;

typedef __bf16 bf16x8 __attribute__((ext_vector_type(8)));
typedef float floatx4 __attribute__((ext_vector_type(4)));
typedef unsigned short ushort8v __attribute__((ext_vector_type(8)));

__device__ __forceinline__ unsigned short f2bf(float f) {
  unsigned u = __builtin_bit_cast(unsigned, f);
  u += 0x7fffu + ((u >> 16) & 1u);  // RNE
  return (unsigned short)(u >> 16);
}

// ---------------- prep: cast both inputs to bf16 + transpose 3 weights ----------------
__global__ __launch_bounds__(256) void prep_kernel(const float4* __restrict__ hs4,
                                                   const float4* __restrict__ rhs4,
                                                   ushort4* __restrict__ hsb4,
                                                   ushort4* __restrict__ rhsb4, int n4,
                                                   const float* __restrict__ Wq,
                                                   const float* __restrict__ Wk,
                                                   const float* __restrict__ Wv,
                                                   unsigned short* __restrict__ Wcat) {
  __shared__ float tile[32][33];
  const int bid = blockIdx.x;
  if (bid < 16384) {
    int i = bid * 256 + threadIdx.x;
    const float4* src;
    ushort4* dst;
    int j;
    if (i < n4) {
      src = hs4; dst = hsb4; j = i;
    } else {
      src = rhs4; dst = rhsb4; j = i - n4;
    }
    float4 v = src[j];
    ushort4 o;
    o.x = f2bf(v.x); o.y = f2bf(v.y); o.z = f2bf(v.z); o.w = f2bf(v.w);
    dst[j] = o;
  } else {
    const int t = bid - 16384;  // 0..3071
    const int z = t >> 10;
    const int r = t & 1023;
    const float* W = (z == 0) ? Wq : (z == 1) ? Wk : Wv;
    unsigned short* Wt = Wcat + (long long)z * D * D;
    const int bx = (r & 31) * 32;  // n block
    const int by = (r >> 5) * 32;  // k block
    const int x = threadIdx.x & 31;
    const int y0 = threadIdx.x >> 5;
    for (int i = 0; i < 4; ++i) {
      int y = y0 + i * 8;
      tile[y][x] = W[(by + y) * D + bx + x];
    }
    __syncthreads();
    for (int i = 0; i < 4; ++i) {
      int y = y0 + i * 8;
      Wt[(long long)(bx + y) * D + by + x] = f2bf(tile[x][y]);
    }
  }
}

// ============ GEMM core: 128x128 tile, BK=32, register-prefetch pipeline ============
// LDS: 64 superrows (2 m-rows) x 8 chunks of 16B; chunk c stored at c^(sr&7) -> every
// 16-lane ds_read/ds_write phase hits each chunk position exactly 2x = conflict-free.
// Pipeline: [barrier; ds_write regs(k); barrier; global_load regs(k+32); ds_read; MFMA]
// -> vmcnt wait lands at next iter's ds_write, i.e. AFTER this iter's compute.

#define GEMM_STAGE_ADDRS(Abase, lda_, Bbase, ldb_)                           \
  const int srow0 = (tid >> 3) * 2 + ((tid >> 2) & 1);                       \
  const int scol0 = (tid & 3) * 8;                                           \
  const unsigned short* aG0 = (Abase) + (long long)(srow0) * (lda_) + scol0; \
  const unsigned short* aG1 = aG0 + (long long)64 * (lda_);                  \
  const unsigned short* bG0 = (Bbase) + (long long)(srow0) * (ldb_) + scol0; \
  const unsigned short* bG1 = bG0 + (long long)64 * (ldb_);                  \
  const int sr0 = tid >> 3;                                                  \
  const int w0 = sr0 * 64 + (((tid & 7) ^ (sr0 & 7)) * 8);                   \
  const int sr1 = sr0 + 32;                                                  \
  const int w1 = sr1 * 64 + (((tid & 7) ^ (sr1 & 7)) * 8);

#define GEMM_FRAG_READ(dst, Buf, wbase)                                      \
  for (int t = 0; t < 4; ++t) {                                              \
    int sr = ((wbase) + t * 16) / 2 + (r15 >> 1);                            \
    int ch = p4q ^ (sr & 7);                                                 \
    dst[t] = *reinterpret_cast<const bf16x8*>(Buf + sr * 64 + ch * 8);       \
  }

// ---------------- fused QKV GEMM: M=8192, N=3072 (1536 blocks, XCD-compact n) ----------
__global__ __launch_bounds__(256) void gemm_qkv_kernel(
    const unsigned short* __restrict__ hsb, const unsigned short* __restrict__ rhsb,
    const unsigned short* __restrict__ Wcat, unsigned short* __restrict__ Qm,
    unsigned short* __restrict__ Km, unsigned short* __restrict__ Vmt,
    const float* __restrict__ bq, const float* __restrict__ bk, const float* __restrict__ bv) {
  __shared__ __align__(16) unsigned short As[128 * 32];
  __shared__ __align__(16) unsigned short Bs[128 * 32];
  const int tid = threadIdx.x;
  const int lane = tid & 63;
  const int w = tid >> 6;
  const int bid = blockIdx.x;
  const int local = bid >> 3;
  const int n_tile = (bid & 7) * 3 + (local % 3);  // bid&7 -> XCD; 3 n-tiles/XCD L2-resident
  const long long m0 = (long long)(local / 3) * 128;
  const long long n0g = (long long)n_tile * 128;
  const int seg = n_tile >> 3;  // 0=Q 1=K 2=V
  const unsigned short* A = ((seg == 0) ? hsb : rhsb) + m0 * D;
  const unsigned short* Bt = Wcat + n0g * D;
  const float* bias = (seg == 0) ? bq : (seg == 1) ? bk : bv;

  GEMM_STAGE_ADDRS(A, D, Bt, D)

  floatx4 zero4 = {0.f, 0.f, 0.f, 0.f};
  floatx4 acc[4][4];
  for (int i = 0; i < 4; ++i)
    for (int j = 0; j < 4; ++j) acc[i][j] = zero4;

  const int r15 = lane & 15;
  const int quad = lane >> 4;
  const int p4q = (r15 & 1) * 4 + quad;
  const int wm = (w >> 1) * 64;
  const int wn = (w & 1) * 64;

  ushort8v sA0 = *(const ushort8v*)aG0, sA1 = *(const ushort8v*)aG1;
  ushort8v sB0 = *(const ushort8v*)bG0, sB1 = *(const ushort8v*)bG1;
  for (int k0 = 0; k0 < D; k0 += 32) {
    __syncthreads();
    *(ushort8v*)(As + w0) = sA0;
    *(ushort8v*)(As + w1) = sA1;
    *(ushort8v*)(Bs + w0) = sB0;
    *(ushort8v*)(Bs + w1) = sB1;
    __syncthreads();
    if (k0 + 32 < D) {
      sA0 = *(const ushort8v*)(aG0 + k0 + 32);
      sA1 = *(const ushort8v*)(aG1 + k0 + 32);
      sB0 = *(const ushort8v*)(bG0 + k0 + 32);
      sB1 = *(const ushort8v*)(bG1 + k0 + 32);
    }
    bf16x8 af[4], bfr[4];
    GEMM_FRAG_READ(af, As, wm)
    GEMM_FRAG_READ(bfr, Bs, wn)
    for (int mt = 0; mt < 4; ++mt)
      for (int nt = 0; nt < 4; ++nt)
        acc[mt][nt] =
            __builtin_amdgcn_mfma_f32_16x16x32_bf16(af[mt], bfr[nt], acc[mt][nt], 0, 0, 0);
  }

  const long long nloc0 = n0g & 1023;
  for (int mt = 0; mt < 4; ++mt) {
    for (int nt = 0; nt < 4; ++nt) {
      const long long mrow = m0 + wm + mt * 16 + quad * 4;
      const long long nc = nloc0 + wn + nt * 16 + r15;
      const float bval = bias[nc];
      floatx4 v = acc[mt][nt];
      for (int e = 0; e < 4; ++e) {
        float val = v[e] + bval;
        long long m = mrow + e;
        if (seg == 0) {
          Qm[m * D + nc] = f2bf(val);
        } else if (seg == 1) {
          Km[m * D + nc] = f2bf(val);
        } else {
          Vmt[(m >> 10) * (long long)(S * D) + nc * S + (m & 1023)] = f2bf(val);
        }
      }
    }
  }
}

// ---------------- batched NT GEMM, batch = bid&7 (XCD-local) ----------------
// MODE 2: C fp32 row-major: z*strideC + m*S + n, * alpha            (scores)
// MODE 3: C fp32 permuted: z*strideC + (n>>6)*S*64 + m*64 + (n&63)  (ctx)
template <int MODE>
__global__ __launch_bounds__(256) void gemm_nt_kernel(
    const unsigned short* __restrict__ A, int lda, long long strideA,
    const unsigned short* __restrict__ Bt, int ldb, long long strideB, float* __restrict__ C,
    long long strideC, float alpha, int K) {
  __shared__ __align__(16) unsigned short As[128 * 32];
  __shared__ __align__(16) unsigned short Bs[128 * 32];
  const int tid = threadIdx.x;
  const int lane = tid & 63;
  const int w = tid >> 6;
  const int bid = blockIdx.x;
  const int z = bid & 7;       // batch == XCD
  const int local = bid >> 3;  // 0..63
  const long long m0 = (long long)(local & 7) * 128;
  const long long n0 = (long long)(local >> 3) * 128;
  const unsigned short* Ab = A + (long long)z * strideA + m0 * lda;
  const unsigned short* Bb = Bt + (long long)z * strideB + n0 * ldb;

  GEMM_STAGE_ADDRS(Ab, lda, Bb, ldb)

  floatx4 zero4 = {0.f, 0.f, 0.f, 0.f};
  floatx4 acc[4][4];
  for (int i = 0; i < 4; ++i)
    for (int j = 0; j < 4; ++j) acc[i][j] = zero4;

  const int r15 = lane & 15;
  const int quad = lane >> 4;
  const int p4q = (r15 & 1) * 4 + quad;
  const int wm = (w >> 1) * 64;
  const int wn = (w & 1) * 64;

  ushort8v sA0 = *(const ushort8v*)aG0, sA1 = *(const ushort8v*)aG1;
  ushort8v sB0 = *(const ushort8v*)bG0, sB1 = *(const ushort8v*)bG1;
  for (int k0 = 0; k0 < K; k0 += 32) {
    __syncthreads();
    *(ushort8v*)(As + w0) = sA0;
    *(ushort8v*)(As + w1) = sA1;
    *(ushort8v*)(Bs + w0) = sB0;
    *(ushort8v*)(Bs + w1) = sB1;
    __syncthreads();
    if (k0 + 32 < K) {
      sA0 = *(const ushort8v*)(aG0 + k0 + 32);
      sA1 = *(const ushort8v*)(aG1 + k0 + 32);
      sB0 = *(const ushort8v*)(bG0 + k0 + 32);
      sB1 = *(const ushort8v*)(bG1 + k0 + 32);
    }
    bf16x8 af[4], bfr[4];
    GEMM_FRAG_READ(af, As, wm)
    GEMM_FRAG_READ(bfr, Bs, wn)
    for (int mt = 0; mt < 4; ++mt)
      for (int nt = 0; nt < 4; ++nt)
        acc[mt][nt] =
            __builtin_amdgcn_mfma_f32_16x16x32_bf16(af[mt], bfr[nt], acc[mt][nt], 0, 0, 0);
  }

  for (int mt = 0; mt < 4; ++mt) {
    for (int nt = 0; nt < 4; ++nt) {
      const long long mrow = m0 + wm + mt * 16 + quad * 4;
      const long long ncol = n0 + wn + nt * 16 + r15;
      floatx4 v = acc[mt][nt];
      for (int e = 0; e < 4; ++e) {
        float val = v[e] * alpha;
        long long m = mrow + e;
        if constexpr (MODE == 2) {
          C[(long long)z * strideC + m * S + ncol] = val;
        } else {
          C[(long long)z * strideC + (ncol >> 6) * (long long)(S * 64) + m * 64 + (ncol & 63)] =
              val;
        }
      }
    }
  }
}

// ---------------- masked softmax; bf16 probs in-place (row stride 2048 elems) ----------
__global__ __launch_bounds__(256) void softmax_kernel(const float* scores,
                                                      const float* __restrict__ mask,
                                                      unsigned short* probs) {
  const int bid = blockIdx.x;
  const long long row = (long long)(bid & 7) * 1024 + (bid >> 3);  // batch == XCD
  const float4* s4 = (const float4*)(scores + row * S);
  const float4* m4 = (const float4*)(mask + row * S);
  ushort4* p4 = (ushort4*)(probs + row * 2048);
  const int tid = threadIdx.x;
  const int lane = tid & 63, w = tid >> 6;
  float4 sv = s4[tid];
  float4 mv = m4[tid];
  float v[4] = {sv.x + (1.0f - mv.x) * -1e9f, sv.y + (1.0f - mv.y) * -1e9f,
                sv.z + (1.0f - mv.z) * -1e9f, sv.w + (1.0f - mv.w) * -1e9f};
  float mx = fmaxf(fmaxf(v[0], v[1]), fmaxf(v[2], v[3]));
  for (int off = 32; off; off >>= 1) mx = fmaxf(mx, __shfl_xor(mx, off, 64));
  __shared__ float redm[4], reds[4];
  if (lane == 0) redm[w] = mx;
  __syncthreads();  // orders all scores-reads before the in-place probs writes too
  mx = fmaxf(fmaxf(redm[0], redm[1]), fmaxf(redm[2], redm[3]));
  float sum = 0.f;
  for (int i = 0; i < 4; ++i) {
    v[i] = __expf(v[i] - mx);
    sum += v[i];
  }
  for (int off = 32; off; off >>= 1) sum += __shfl_xor(sum, off, 64);
  if (lane == 0) reds[w] = sum;
  __syncthreads();
  sum = reds[0] + reds[1] + reds[2] + reds[3];
  float inv = 1.0f / sum;
  ushort4 o;
  o.x = f2bf(v[0] * inv);
  o.y = f2bf(v[1] * inv);
  o.z = f2bf(v[2] * inv);
  o.w = f2bf(v[3] * inv);
  p4[tid] = o;
}

extern "C" void kernel_launch(void* const* d_in, const int* in_sizes, int n_in, void* d_out,
                              int out_size, void* d_ws, size_t ws_size, hipStream_t stream) {
  const float* hs = (const float*)d_in[0];
  const float* rhs = (const float*)d_in[1];
  const float* mask = (const float*)d_in[2];
  const float* Wq = (const float*)d_in[3];
  const float* bq = (const float*)d_in[4];
  const float* Wk = (const float*)d_in[5];
  const float* bk = (const float*)d_in[6];
  const float* Wv = (const float*)d_in[7];
  const float* bv = (const float*)d_in[8];
  float* out = (float*)d_out;
  char* ws = (char*)d_ws;
  const size_t MB = 1ull << 20;
  // layout: Wcat(6MB) | hs_bf16(16) | rhs_bf16(16) | Qm(16) | Km(16) | Vm_t(16) = 86 MB
  // scores (32MB fp32) overlays hs_bf16+rhs_bf16 (dead after QKV GEMM); probs bf16 in-place.
  unsigned short* Wcat = (unsigned short*)(ws + 0 * MB);
  unsigned short* hsb = (unsigned short*)(ws + 6 * MB);
  unsigned short* rhsb = (unsigned short*)(ws + 22 * MB);
  unsigned short* Qm = (unsigned short*)(ws + 38 * MB);
  unsigned short* Km = (unsigned short*)(ws + 54 * MB);
  unsigned short* Vmt = (unsigned short*)(ws + 70 * MB);
  float* scores = (float*)(ws + 6 * MB);
  unsigned short* probs = (unsigned short*)scores;

  const int n4 = NB * S * D / 4;  // 2M float4 per input
  prep_kernel<<<16384 + 3072, 256, 0, stream>>>((const float4*)hs, (const float4*)rhs,
                                                (ushort4*)hsb, (ushort4*)rhsb, n4, Wq, Wk, Wv,
                                                Wcat);

  // fused QKV projections: M=8192, N=3072, 1536 blocks, XCD-compact n
  gemm_qkv_kernel<<<1536, 256, 0, stream>>>(hsb, rhsb, Wcat, Qm, Km, Vmt, bq, bk, bv);

  // scores[b] = Qm[b] * Km[b]^T / 8   (batched, fp32 out, batch==XCD)
  gemm_nt_kernel<2><<<512, 256, 0, stream>>>(Qm, D, (long long)S * D, Km, D, (long long)S * D,
                                             scores, (long long)S * S, 0.125f, D);
  softmax_kernel<<<NB * S, 256, 0, stream>>>(scores, mask, probs);
  // ctx[b] = probs[b] * Vm_t[b]^T, permuted fp32 store into d_out
  gemm_nt_kernel<3><<<512, 256, 0, stream>>>(probs, 2048, (long long)S * 2048, Vmt, D,
                                             (long long)S * D, out, (long long)S * D, 1.f, D);
}